// Round 11
// baseline (148.669 us; speedup 1.0000x reference)
//
#include <hip/hip_runtime.h>

#define IN_F 128
#define OUT_F 128
#define BROWS 64        // destination rows per bucket (nb=782)
#define BCAP  2048      // slab capacity; E[edges/bucket]=1024 -> P(overflow)~0
#define CHUNK 2048      // edges per bin block (391 blocks; 8 iters/lane)
#define NBMAX 1024      // LDS histogram capacity (>= nb = 782)

typedef __attribute__((ext_vector_type(8))) short short8;   // 8 bf16
typedef __attribute__((ext_vector_type(4))) float floatx4;  // MFMA C/D

__device__ __forceinline__ short f2bf(float f) {
  union { float f; unsigned u; } v; v.f = f;
  unsigned u = v.u;
  unsigned r = (u + 0x7fffu + ((u >> 16) & 1u)) >> 16;
  return (short)r;
}
__device__ __forceinline__ float bflo(unsigned u) { return __uint_as_float(u << 16); }
__device__ __forceinline__ float bfhi(unsigned u) { return __uint_as_float(u & 0xffff0000u); }

// ---------------------------------------------------------------------------
// Prep: wt[n][k] = bf16(W[k][n]) AND cursor[b] = b*BCAP. 64x256 covers both.
// ---------------------------------------------------------------------------
__global__ __launch_bounds__(256) void prep_all(const float* __restrict__ w,
                                                short* __restrict__ wt,
                                                int* __restrict__ cursor, int nb) {
  int i = blockIdx.x * 256 + threadIdx.x;   // i = n*128 + k
  int n = i >> 7, k = i & 127;
  wt[i] = f2bf(w[k * 128 + n]);
  if (i < nb) cursor[i] = i * BCAP;
}

// ---------------------------------------------------------------------------
// Merged: blocks [0, n_tiles) = GEMM 64x128 tiles; [n_tiles, +n_chunks) = bin
// 2048-edge chunks. Bin block serial depth (8 iters/lane) now comparable to
// the gemm span, so merged wall time ~ max(gemm, bin) ~ 14 us (r10 lesson:
// the long pole was the 26-us bin block, not CU idleness).
// ---------------------------------------------------------------------------
__global__ __launch_bounds__(256) void gemm_bin(const float* __restrict__ x,
                                                const short* __restrict__ wt,
                                                unsigned short* __restrict__ sup,
                                                const int* __restrict__ erow,
                                                const int* __restrict__ ecol,
                                                const float* __restrict__ eval_,
                                                int* __restrict__ cursor,
                                                int2* __restrict__ slab,
                                                int n_nodes, int n_edges,
                                                int nb, int n_tiles) {
  __shared__ __align__(16) unsigned short stile[4][16 * 136];  // gemm epilogue (17 KB)
  __shared__ int lhist[NBMAX];                                 // bin path (4 KB)
  const int t = threadIdx.x;

  if ((int)blockIdx.x < n_tiles) {
    // ---------------- GEMM tile: 64 rows x 128 cols ----------------
    const int wv   = t >> 6;
    const int lane = t & 63;
    const int m    = lane & 15;
    const int q    = lane >> 4;
    const int row  = blockIdx.x * 64 + wv * 16 + m;

    floatx4 acc[8];
#pragma unroll
    for (int k = 0; k < 8; ++k) acc[k] = (floatx4)(0.f);

#pragma unroll
    for (int kk = 0; kk < 4; ++kk) {
      short8 a;
      if (row < n_nodes) {
        const float4* px = (const float4*)(x + (size_t)row * IN_F + kk * 32 + q * 8);
        float4 lo = px[0], hi = px[1];
        a[0] = f2bf(lo.x); a[1] = f2bf(lo.y); a[2] = f2bf(lo.z); a[3] = f2bf(lo.w);
        a[4] = f2bf(hi.x); a[5] = f2bf(hi.y); a[6] = f2bf(hi.z); a[7] = f2bf(hi.w);
      } else {
        a = (short8)(0);
      }
#pragma unroll
      for (int k = 0; k < 8; ++k) {
        short8 b = *(const short8*)(wt + (size_t)(16 * k + m) * 128 + kk * 32 + q * 8);
        acc[k] = __builtin_amdgcn_mfma_f32_16x16x32_bf16(a, b, acc[k], 0, 0, 0);
      }
    }
    // stage C tile in LDS (stride 136 -> 2-way aliasing = free), coalesced stores
#pragma unroll
    for (int r = 0; r < 4; ++r)
#pragma unroll
      for (int k = 0; k < 8; ++k)
        stile[wv][(q * 4 + r) * 136 + 16 * k + m] = (unsigned short)f2bf(acc[k][r]);
#pragma unroll
    for (int p = 0; p < 4; ++p) {
      int row_l = p * 4 + (lane >> 4);
      int row_g = blockIdx.x * 64 + wv * 16 + row_l;
      if (row_g < n_nodes) {
        uint4 v = *(const uint4*)&stile[wv][row_l * 136 + (lane & 15) * 8];
        *(uint4*)(sup + (size_t)row_g * OUT_F + (lane & 15) * 8) = v;
      }
    }
  } else {
    // ---------------- Bin chunk: 2048 edges, bucket-grouped writes ----------
    for (int b = t; b < nb; b += 256) lhist[b] = 0;
    __syncthreads();

    const int base = (blockIdx.x - n_tiles) * CHUNK;
    int meta[8], col[8]; float val[8];
#pragma unroll
    for (int i = 0; i < 8; ++i) {
      int e = base + i * 256 + t;
      meta[i] = -1;
      if (e < n_edges) {
        int r  = erow[e];
        col[i] = ecol[e];
        val[i] = eval_[e];
        int bk = r >> 6, rl = r & 63;
        int rank = atomicAdd(&lhist[bk], 1);            // rank within (chunk,bucket)
        meta[i] = (bk << 18) | (rl << 12) | rank;       // 10b | 6b | 12b
      }
    }
    __syncthreads();
    for (int bk = t; bk < nb; bk += 256) {
      int c = lhist[bk];
      lhist[bk] = c ? atomicAdd(&cursor[bk], c) : 0;    // reserve slab space
    }
    __syncthreads();
#pragma unroll
    for (int i = 0; i < 8; ++i) {
      if (meta[i] >= 0) {
        int bk = meta[i] >> 18, rl = (meta[i] >> 12) & 63, rank = meta[i] & 0xfff;
        int pos = lhist[bk] + rank;
        if (pos < (bk + 1) * BCAP)                      // overflow guard (never fires)
          slab[pos] = make_int2(col[i] | (rl << 16), __float_as_int(val[i]));
      }
    }
  }
}

// ---------------------------------------------------------------------------
// SpMM: one block per 64-row bucket. Pass 1 stages the bucket's records in
// REGISTERS (<=8/thread) while counting rows; pass 2 scatters from registers
// (no second slab read). Gather: DEPTH-8 ring -> 8 outstanding 256 B gathers
// per wave (grid-bound at ~3 blocks/CU, so the extra VGPRs are free).
// ---------------------------------------------------------------------------
__global__ __launch_bounds__(256) void spmm_sorted(const int* __restrict__ cursor,
                                                   const int2* __restrict__ slab,
                                                   const uint4* __restrict__ supv,
                                                   const float* __restrict__ bias,
                                                   float* __restrict__ out,
                                                   int n_nodes) {
  __shared__ int2 srec[BCAP];        // 16 KB row-sorted records
  __shared__ int  roff[BROWS + 1];
  __shared__ int  rcur[BROWS];
  const int t = threadIdx.x, b = blockIdx.x;
  const int start = b * BCAP;
  const int cnt = min(cursor[b] - start, BCAP);
  const int wv = t >> 6, lane = t & 63;

  if (t < BROWS) rcur[t] = 0;
  __syncthreads();
  // pass 1: stage records in registers + per-row counts (single slab read)
  int2 stg[8];
#pragma unroll
  for (int i = 0; i < 8; ++i) {
    int idx = i * 256 + t;
    stg[i] = make_int2(-1, 0);
    if (idx < cnt) {
      int2 r = slab[start + idx];
      stg[i] = r;
      atomicAdd(&rcur[(r.x >> 16) & 63], 1);
    }
  }
  __syncthreads();
  // wave-0 shfl scan of 64 bins -> exclusive offsets
  if (wv == 0) {
    int c = rcur[lane];
    int inc = c;
#pragma unroll
    for (int d = 1; d < 64; d <<= 1) {
      int u = __shfl_up(inc, d);
      if (lane >= d) inc += u;
    }
    roff[lane + 1] = inc;
    if (lane == 0) roff[0] = 0;
  }
  __syncthreads();
  if (t < BROWS) rcur[t] = roff[t];
  __syncthreads();
  // pass 2: scatter from registers, row-sorted into LDS
#pragma unroll
  for (int i = 0; i < 8; ++i) {
    if (stg[i].x != -1) {
      int p = atomicAdd(&rcur[(stg[i].x >> 16) & 63], 1);
      srec[p] = stg[i];
    }
  }
  __syncthreads();

  // gather: 4 its x (4 rows/wave, 16 lanes/row, uint4 = 8 bf16 feats/lane)
  const int g = lane >> 4, s = lane & 15;
  const float4* bp = (const float4*)bias + s * 2;
  const float4 b0 = bp[0], b1 = bp[1];

#pragma unroll
  for (int it = 0; it < 4; ++it) {
    const int rl = it * 16 + wv * 4 + g;
    const int s0 = roff[rl];
    const int c  = roff[rl + 1] - s0;
    int mx = max(c, __shfl_xor(c, 16));
    mx = max(mx, __shfl_xor(mx, 32));

    float a0 = 0.f, a1 = 0.f, a2 = 0.f, a3 = 0.f,
          a4 = 0.f, a5 = 0.f, a6 = 0.f, a7 = 0.f;

    int2  rec[8];
    uint4 sv[8];
#pragma unroll
    for (int k = 0; k < 8; ++k)
      rec[k] = (k < c) ? srec[s0 + k] : make_int2(0, 0);
#pragma unroll
    for (int k = 0; k < 8; ++k)
      sv[k] = supv[(size_t)(rec[k].x & 0xffff) * 16 + s];

    for (int j = 0; j < mx; j += 8) {
#pragma unroll
      for (int k = 0; k < 8; ++k) {
        const int jj = j + k;
        int2 recn = (jj + 8 < c) ? srec[s0 + jj + 8] : make_int2(0, 0);
        uint4 svn = supv[(size_t)(recn.x & 0xffff) * 16 + s];   // issue load jj+8
        float v = (jj < c) ? __int_as_float(rec[k].y) : 0.f;
        a0 = fmaf(v, bflo(sv[k].x), a0);
        a1 = fmaf(v, bfhi(sv[k].x), a1);
        a2 = fmaf(v, bflo(sv[k].y), a2);
        a3 = fmaf(v, bfhi(sv[k].y), a3);
        a4 = fmaf(v, bflo(sv[k].z), a4);
        a5 = fmaf(v, bfhi(sv[k].z), a5);
        a6 = fmaf(v, bflo(sv[k].w), a6);
        a7 = fmaf(v, bfhi(sv[k].w), a7);
        rec[k] = recn; sv[k] = svn;
      }
    }

    const int row = b * BROWS + rl;
    if (row < n_nodes) {
      float4* op = (float4*)(out + (size_t)row * OUT_F + s * 8);
      op[0] = make_float4(a0 + b0.x, a1 + b0.y, a2 + b0.z, a3 + b0.w);
      op[1] = make_float4(a4 + b1.x, a5 + b1.y, a6 + b1.z, a7 + b1.w);
    }
  }
}

extern "C" void kernel_launch(void* const* d_in, const int* in_sizes, int n_in,
                              void* d_out, int out_size, void* d_ws, size_t ws_size,
                              hipStream_t stream) {
  const float* x     = (const float*)d_in[0];
  const int*   erow  = (const int*)d_in[1];
  const int*   ecol  = (const int*)d_in[2];
  const float* eval_ = (const float*)d_in[3];
  const float* w     = (const float*)d_in[4];
  const float* bias  = (const float*)d_in[5];
  float* out = (float*)d_out;

  const int n_nodes  = in_sizes[0] / IN_F;
  const int n_edges  = in_sizes[1];
  const int nb       = (n_nodes + BROWS - 1) / BROWS;   // 782
  const int n_tiles  = (n_nodes + 63) / 64;             // 782
  const int n_chunks = (n_edges + CHUNK - 1) / CHUNK;   // 391

  char* ws = (char*)d_ws;
  size_t off = 0;
  auto carve = [&](size_t bytes) { void* p = ws + off; off = (off + bytes + 255) & ~(size_t)255; return p; };
  unsigned short* sup = (unsigned short*)carve((size_t)n_nodes * OUT_F * sizeof(unsigned short)); // 12.8 MB
  short* wt           = (short*)carve((size_t)IN_F * OUT_F * sizeof(short));                      // 32 KB
  int*   cursor       = (int*)  carve((size_t)nb * sizeof(int));
  int2*  slab         = (int2*) carve((size_t)nb * BCAP * sizeof(int2));                          // 12.8 MB

  prep_all<<<64, 256, 0, stream>>>(w, wt, cursor, nb);
  gemm_bin<<<n_tiles + n_chunks, 256, 0, stream>>>(x, wt, sup, erow, ecol, eval_,
                                                   cursor, slab, n_nodes, n_edges,
                                                   nb, n_tiles);
  spmm_sorted<<<nb, 256, 0, stream>>>(cursor, slab, (const uint4*)sup, bias, out, n_nodes);
}

// Round 12
// 137.209 us; speedup vs baseline: 1.0835x; 1.0835x over previous
//
#include <hip/hip_runtime.h>

#define IN_F 128
#define OUT_F 128
#define BROWS 64        // destination rows per bucket (nb=782)
#define BCAP  2048      // slab capacity; E[edges/bucket]=1024 -> P(overflow)~0
#define CHUNK 4096      // edges per bin block (196 blocks; 16 iters/lane) [r10-proven]
#define NBMAX 1024      // LDS histogram capacity (>= nb = 782)

typedef __attribute__((ext_vector_type(8))) short short8;   // 8 bf16
typedef __attribute__((ext_vector_type(4))) float floatx4;  // MFMA C/D

__device__ __forceinline__ short f2bf(float f) {
  union { float f; unsigned u; } v; v.f = f;
  unsigned u = v.u;
  unsigned r = (u + 0x7fffu + ((u >> 16) & 1u)) >> 16;
  return (short)r;
}
__device__ __forceinline__ float bflo(unsigned u) { return __uint_as_float(u << 16); }
__device__ __forceinline__ float bfhi(unsigned u) { return __uint_as_float(u & 0xffff0000u); }

// ---------------------------------------------------------------------------
// Prep: wt[n][k] = bf16(W[k][n]) AND cursor[b] = b*BCAP. 64x256 covers both.
// ---------------------------------------------------------------------------
__global__ __launch_bounds__(256) void prep_all(const float* __restrict__ w,
                                                short* __restrict__ wt,
                                                int* __restrict__ cursor, int nb) {
  int i = blockIdx.x * 256 + threadIdx.x;   // i = n*128 + k
  int n = i >> 7, k = i & 127;
  wt[i] = f2bf(w[k * 128 + n]);
  if (i < nb) cursor[i] = i * BCAP;
}

// ---------------------------------------------------------------------------
// Merged: blocks [0, n_tiles) = GEMM 64x128 tiles; [n_tiles, +n_chunks) = bin
// 4096-edge chunks. (byte-identical to round-10's proven kernel)
// ---------------------------------------------------------------------------
__global__ __launch_bounds__(256) void gemm_bin(const float* __restrict__ x,
                                                const short* __restrict__ wt,
                                                unsigned short* __restrict__ sup,
                                                const int* __restrict__ erow,
                                                const int* __restrict__ ecol,
                                                const float* __restrict__ eval_,
                                                int* __restrict__ cursor,
                                                int2* __restrict__ slab,
                                                int n_nodes, int n_edges,
                                                int nb, int n_tiles) {
  __shared__ __align__(16) unsigned short stile[4][16 * 136];  // gemm epilogue (17 KB)
  __shared__ int lhist[NBMAX];                                 // bin path (4 KB)
  const int t = threadIdx.x;

  if ((int)blockIdx.x < n_tiles) {
    // ---------------- GEMM tile: 64 rows x 128 cols ----------------
    const int wv   = t >> 6;
    const int lane = t & 63;
    const int m    = lane & 15;
    const int q    = lane >> 4;
    const int row  = blockIdx.x * 64 + wv * 16 + m;

    floatx4 acc[8];
#pragma unroll
    for (int k = 0; k < 8; ++k) acc[k] = (floatx4)(0.f);

#pragma unroll
    for (int kk = 0; kk < 4; ++kk) {
      short8 a;
      if (row < n_nodes) {
        const float4* px = (const float4*)(x + (size_t)row * IN_F + kk * 32 + q * 8);
        float4 lo = px[0], hi = px[1];
        a[0] = f2bf(lo.x); a[1] = f2bf(lo.y); a[2] = f2bf(lo.z); a[3] = f2bf(lo.w);
        a[4] = f2bf(hi.x); a[5] = f2bf(hi.y); a[6] = f2bf(hi.z); a[7] = f2bf(hi.w);
      } else {
        a = (short8)(0);
      }
#pragma unroll
      for (int k = 0; k < 8; ++k) {
        short8 b = *(const short8*)(wt + (size_t)(16 * k + m) * 128 + kk * 32 + q * 8);
        acc[k] = __builtin_amdgcn_mfma_f32_16x16x32_bf16(a, b, acc[k], 0, 0, 0);
      }
    }
    // stage C tile in LDS (stride 136 -> 2-way aliasing = free), coalesced stores
#pragma unroll
    for (int r = 0; r < 4; ++r)
#pragma unroll
      for (int k = 0; k < 8; ++k)
        stile[wv][(q * 4 + r) * 136 + 16 * k + m] = (unsigned short)f2bf(acc[k][r]);
#pragma unroll
    for (int p = 0; p < 4; ++p) {
      int row_l = p * 4 + (lane >> 4);
      int row_g = blockIdx.x * 64 + wv * 16 + row_l;
      if (row_g < n_nodes) {
        uint4 v = *(const uint4*)&stile[wv][row_l * 136 + (lane & 15) * 8];
        *(uint4*)(sup + (size_t)row_g * OUT_F + (lane & 15) * 8) = v;
      }
    }
  } else {
    // ---------------- Bin chunk: 4096 edges, bucket-grouped writes ----------
    for (int b = t; b < nb; b += 256) lhist[b] = 0;
    __syncthreads();

    const int base = (blockIdx.x - n_tiles) * CHUNK;
    int meta[16], col[16]; float val[16];
#pragma unroll
    for (int i = 0; i < 16; ++i) {
      int e = base + i * 256 + t;
      meta[i] = -1;
      if (e < n_edges) {
        int r  = erow[e];
        col[i] = ecol[e];
        val[i] = eval_[e];
        int bk = r >> 6, rl = r & 63;
        int rank = atomicAdd(&lhist[bk], 1);            // rank within (chunk,bucket)
        meta[i] = (bk << 18) | (rl << 12) | rank;       // 10b | 6b | 12b
      }
    }
    __syncthreads();
    for (int bk = t; bk < nb; bk += 256) {
      int c = lhist[bk];
      lhist[bk] = c ? atomicAdd(&cursor[bk], c) : 0;    // reserve slab space
    }
    __syncthreads();
#pragma unroll
    for (int i = 0; i < 16; ++i) {
      if (meta[i] >= 0) {
        int bk = meta[i] >> 18, rl = (meta[i] >> 12) & 63, rank = meta[i] & 0xfff;
        int pos = lhist[bk] + rank;
        if (pos < (bk + 1) * BCAP)                      // overflow guard (never fires)
          slab[pos] = make_int2(col[i] | (rl << 16), __float_as_int(val[i]));
      }
    }
  }
}

// ---------------------------------------------------------------------------
// SpMM: one block per 64-row bucket. Counting-sort into LDS (r10-identical),
// then BALANCED gather: 16 groups x 16 lanes; group g owns the row-aligned
// record range nearest [g*cnt/16, (g+1)*cnt/16) via binary search on roff.
// Each row is owned by exactly one group -> acc flushes straight to global
// out (+bias), no atomics, no separate epilogue. Flat edge loop with the
// r10-proven depth-4 ring runs across row boundaries.
// ---------------------------------------------------------------------------
__global__ __launch_bounds__(256) void spmm_sorted(const int* __restrict__ cursor,
                                                   const int2* __restrict__ slab,
                                                   const uint4* __restrict__ supv,
                                                   const float* __restrict__ bias,
                                                   float* __restrict__ out,
                                                   int n_nodes) {
  __shared__ int2 srec[BCAP];        // 16 KB row-sorted records
  __shared__ int  roff[BROWS + 1];
  __shared__ int  rcur[BROWS];
  const int t = threadIdx.x, b = blockIdx.x;
  const int start = b * BCAP;
  const int cnt = min(cursor[b] - start, BCAP);
  const int wv = t >> 6, lane = t & 63;

  if (t < BROWS) rcur[t] = 0;
  __syncthreads();
  // pass 1: per-row counts (coalesced stream)
  for (int i = t; i < cnt; i += 256)
    atomicAdd(&rcur[(slab[start + i].x >> 16) & 63], 1);
  __syncthreads();
  // wave-0 shfl scan of 64 bins -> exclusive offsets
  if (wv == 0) {
    int c = rcur[lane];
    int inc = c;
#pragma unroll
    for (int d = 1; d < 64; d <<= 1) {
      int u = __shfl_up(inc, d);
      if (lane >= d) inc += u;
    }
    roff[lane + 1] = inc;
    if (lane == 0) roff[0] = 0;
  }
  __syncthreads();
  if (t < BROWS) rcur[t] = roff[t];
  __syncthreads();
  // pass 2: scatter row-sorted into LDS (slab segment L2-hot from pass 1)
  for (int i = t; i < cnt; i += 256) {
    int2 r = slab[start + i];
    int p = atomicAdd(&rcur[(r.x >> 16) & 63], 1);
    srec[p] = r;
  }
  __syncthreads();

  // ---- balanced gather ----
  const int gid = t >> 4;            // group 0..15
  const int s   = t & 15;            // feature segment (8 feats, uint4)
  const float4* bp = (const float4*)bias + s * 2;
  const float4 b0 = bp[0], b1 = bp[1];
  const int row0 = b * BROWS;

  // row-aligned equal-edge split points (identical formula in every group
  // => disjoint ranges partitioning [0,64))
  int ra, rb;
  {
    int tgt = (gid * cnt) >> 4;
    int lo = 0, hi = 64;
    while (lo < hi) { int m = (lo + hi) >> 1; if (roff[m] >= tgt) hi = m; else lo = m + 1; }
    ra = lo;
    if (gid == 15) rb = 64;
    else {
      tgt = ((gid + 1) * cnt) >> 4;
      lo = 0; hi = 64;
      while (lo < hi) { int m = (lo + hi) >> 1; if (roff[m] >= tgt) hi = m; else lo = m + 1; }
      rb = lo;
    }
  }

  if (ra < rb) {
    const int j0 = roff[ra];
    const int j1 = roff[rb];
    int cur  = ra;
    int nend = roff[cur + 1];

    float a0 = 0.f, a1 = 0.f, a2 = 0.f, a3 = 0.f,
          a4 = 0.f, a5 = 0.f, a6 = 0.f, a7 = 0.f;

    int2  rec[4];
    uint4 sv[4];
#pragma unroll
    for (int k = 0; k < 4; ++k)
      rec[k] = (j0 + k < j1) ? srec[j0 + k] : make_int2(0, 0);
#pragma unroll
    for (int k = 0; k < 4; ++k)
      sv[k] = supv[(size_t)(rec[k].x & 0xffff) * 16 + s];

    for (int jb = j0; jb < j1; jb += 4) {
#pragma unroll
      for (int k = 0; k < 4; ++k) {
        const int jj = jb + k;
        if (jj < j1) {
          while (jj == nend) {           // row boundary: flush owned row
            if (row0 + cur < n_nodes) {
              float4* op = (float4*)(out + (size_t)(row0 + cur) * OUT_F + s * 8);
              op[0] = make_float4(a0 + b0.x, a1 + b0.y, a2 + b0.z, a3 + b0.w);
              op[1] = make_float4(a4 + b1.x, a5 + b1.y, a6 + b1.z, a7 + b1.w);
            }
            a0 = a1 = a2 = a3 = a4 = a5 = a6 = a7 = 0.f;
            ++cur;
            nend = roff[cur + 1];
          }
          float v = __int_as_float(rec[k].y);
          a0 = fmaf(v, bflo(sv[k].x), a0);
          a1 = fmaf(v, bfhi(sv[k].x), a1);
          a2 = fmaf(v, bflo(sv[k].y), a2);
          a3 = fmaf(v, bfhi(sv[k].y), a3);
          a4 = fmaf(v, bflo(sv[k].z), a4);
          a5 = fmaf(v, bfhi(sv[k].z), a5);
          a6 = fmaf(v, bflo(sv[k].w), a6);
          a7 = fmaf(v, bfhi(sv[k].w), a7);
          int2 recn = (jj + 4 < j1) ? srec[jj + 4] : make_int2(0, 0);
          rec[k] = recn;
          sv[k] = supv[(size_t)(recn.x & 0xffff) * 16 + s];   // issue load jj+4
        }
      }
    }
    // trailing: flush current row's acc, then bias-only for remaining rows
    while (cur < rb) {
      if (row0 + cur < n_nodes) {
        float4* op = (float4*)(out + (size_t)(row0 + cur) * OUT_F + s * 8);
        op[0] = make_float4(a0 + b0.x, a1 + b0.y, a2 + b0.z, a3 + b0.w);
        op[1] = make_float4(a4 + b1.x, a5 + b1.y, a6 + b1.z, a7 + b1.w);
      }
      a0 = a1 = a2 = a3 = a4 = a5 = a6 = a7 = 0.f;
      ++cur;
    }
  }
}

extern "C" void kernel_launch(void* const* d_in, const int* in_sizes, int n_in,
                              void* d_out, int out_size, void* d_ws, size_t ws_size,
                              hipStream_t stream) {
  const float* x     = (const float*)d_in[0];
  const int*   erow  = (const int*)d_in[1];
  const int*   ecol  = (const int*)d_in[2];
  const float* eval_ = (const float*)d_in[3];
  const float* w     = (const float*)d_in[4];
  const float* bias  = (const float*)d_in[5];
  float* out = (float*)d_out;

  const int n_nodes  = in_sizes[0] / IN_F;
  const int n_edges  = in_sizes[1];
  const int nb       = (n_nodes + BROWS - 1) / BROWS;   // 782
  const int n_tiles  = (n_nodes + 63) / 64;             // 782
  const int n_chunks = (n_edges + CHUNK - 1) / CHUNK;   // 196

  char* ws = (char*)d_ws;
  size_t off = 0;
  auto carve = [&](size_t bytes) { void* p = ws + off; off = (off + bytes + 255) & ~(size_t)255; return p; };
  unsigned short* sup = (unsigned short*)carve((size_t)n_nodes * OUT_F * sizeof(unsigned short)); // 12.8 MB
  short* wt           = (short*)carve((size_t)IN_F * OUT_F * sizeof(short));                      // 32 KB
  int*   cursor       = (int*)  carve((size_t)nb * sizeof(int));
  int2*  slab         = (int2*) carve((size_t)nb * BCAP * sizeof(int2));                          // 12.8 MB

  prep_all<<<64, 256, 0, stream>>>(w, wt, cursor, nb);
  gemm_bin<<<n_tiles + n_chunks, 256, 0, stream>>>(x, wt, sup, erow, ecol, eval_,
                                                   cursor, slab, n_nodes, n_edges,
                                                   nb, n_tiles);
  spmm_sorted<<<nb, 256, 0, stream>>>(cursor, slab, (const uint4*)sup, bias, out, n_nodes);
}